// Round 5
// baseline (1459.948 us; speedup 1.0000x reference)
//
#include <hip/hip_runtime.h>
#include <stdint.h>

#define KNN 16
#define CLEN 4
#define NB 4
#define NP 8192
#define G 16
#define NC (G * G * G)
#define GLO -4.5f
#define WC 0.5625f
#define INVW 1.7777777777777777f
#define EPS 1e-3f
#define SDEPTH 16
#define NWAVE ((NB * NP) / 64)

// FP-rounding variants verified bit-exact vs reference (rounds 1-4):
//   sq = (x*x + y*y) + z*z   (no fma),  dot = fma chain,  d2 = fma(-2,dot,sqn+sqm)

__device__ __forceinline__ unsigned sp3(unsigned v) {
  v = (v | (v << 16)) & 0x030000FFu;
  v = (v | (v << 8)) & 0x0300F00Fu;
  v = (v | (v << 4)) & 0x030C30C3u;
  v = (v | (v << 2)) & 0x09249249u;
  return v;
}
__device__ __forceinline__ int morton3(int cx, int cy, int cz) {
  return (int)(sp3((unsigned)cx) | (sp3((unsigned)cy) << 1) | (sp3((unsigned)cz) << 2));
}
__device__ __forceinline__ int cell1(float v) {
  int c = (int)floorf((v - GLO) * INVW);
  return min(G - 1, max(0, c));
}

__global__ void bin_kernel(const float* __restrict__ xyz, int* __restrict__ cellid,
                           int* __restrict__ hist) {
  int t = blockIdx.x * blockDim.x + threadIdx.x;
  if (t >= NB * NP) return;
  int b = t >> 13;
  int m = morton3(cell1(xyz[t * 3 + 0]), cell1(xyz[t * 3 + 1]), cell1(xyz[t * 3 + 2]));
  cellid[t] = m;
  atomicAdd(&hist[b * NC + m], 1);
}

__global__ __launch_bounds__(1024) void scan_kernel(const int* __restrict__ hist,
                                                    int* __restrict__ offs) {
  __shared__ int s[1024];
  int b = blockIdx.x, t = threadIdx.x;
  int base = b * NC + t * 4;
  int v0 = hist[base + 0], v1 = hist[base + 1], v2 = hist[base + 2], v3 = hist[base + 3];
  int sum = v0 + v1 + v2 + v3;
  s[t] = sum;
  __syncthreads();
  for (int d = 1; d < 1024; d <<= 1) {
    int x = 0;
    if (t >= d) x = s[t - d];
    __syncthreads();
    if (t >= d) s[t] += x;
    __syncthreads();
  }
  int run = s[t] - sum;  // exclusive
  offs[base + 0] = run; run += v0;
  offs[base + 1] = run; run += v1;
  offs[base + 2] = run; run += v2;
  offs[base + 3] = run;
}

__global__ void scatter_kernel(const float* __restrict__ xyz, const int* __restrict__ cellid,
                               const int* __restrict__ offs, int* __restrict__ cursor,
                               float4* __restrict__ scand, int* __restrict__ sidx) {
#pragma clang fp contract(off)
  int t = blockIdx.x * blockDim.x + threadIdx.x;
  if (t >= NB * NP) return;
  int b = t >> 13, n = t & (NP - 1);
  float x = xyz[t * 3 + 0], y = xyz[t * 3 + 1], z = xyz[t * 3 + 2];
  float sq = (x * x + y * y) + z * z;   // verified non-fma sequence
  int m = cellid[t];
  int pos = offs[b * NC + m] + atomicAdd(&cursor[b * NC + m], 1);
  scand[b * NP + pos] = make_float4(x, y, z, sq);
  sidx[b * NP + pos] = n;
}

// Lex-stable sorted insert: order by (d, idx) ascending. Value chain via med3 is
// tie-safe (pure copies); idx chain uses lex bools. Exact jax.lax.top_k order.
#define INSERT(dv, iv)                                                        \
  do {                                                                        \
    float _d = (dv); int _i = (iv);                                           \
    bool cl[KNN];                                                             \
    _Pragma("unroll")                                                         \
    for (int j = 0; j < KNN; ++j)                                             \
      cl[j] = (dist[j] > _d) || ((dist[j] == _d) && (idx[j] > _i));           \
    _Pragma("unroll")                                                         \
    for (int j = KNN - 1; j >= 1; --j) {                                      \
      dist[j] = __builtin_amdgcn_fmed3f(dist[j - 1], dist[j], _d);            \
      idx[j] = cl[j - 1] ? idx[j - 1] : (cl[j] ? _i : idx[j]);                \
    }                                                                         \
    dist[0] = fminf(dist[0], _d);                                             \
    idx[0] = cl[0] ? _i : idx[0];                                             \
  } while (0)

#define FLUSH()                                                 \
  do {                                                          \
    float2 e[SDEPTH];                                           \
    _Pragma("unroll")                                           \
    for (int j = 0; j < SDEPTH; ++j) e[j] = stk[j][lane];       \
    _Pragma("unroll")                                           \
    for (int j = 0; j < SDEPTH; ++j) {                          \
      if (!__any(j < pc)) break;                                \
      bool act = j < pc;                                        \
      float fd = act ? e[j].x : __builtin_inff();               \
      int fi = __float_as_int(e[j].y);                          \
      INSERT(fd, fi);                                           \
    }                                                           \
    pc = 0;                                                     \
    dmax = dist[KNN - 1];                                       \
  } while (0)

__global__ __launch_bounds__(64) void knnq_kernel(const float4* __restrict__ scand,
                                                  const int* __restrict__ sidx,
                                                  const int* __restrict__ offs,
                                                  const int* __restrict__ hist,
                                                  int* __restrict__ knnt) {
#pragma clang fp contract(off)
  __shared__ float2 stk[SDEPTH][64];
  const int lane = threadIdx.x;
  const int wq = blockIdx.x * 64 + lane;  // sorted slot
  const int b = wq >> 13;
  const int bbase = b * NP;
  const float4 qd = scand[wq];
  const int orig = sidx[wq];

  // wave bbox (float) of query coords, then cell bbox
  float blx = qd.x, bhx = qd.x, bly = qd.y, bhy = qd.y, blz = qd.z, bhz = qd.z;
#pragma unroll
  for (int o = 1; o < 64; o <<= 1) {
    blx = fminf(blx, __shfl_xor(blx, o)); bhx = fmaxf(bhx, __shfl_xor(bhx, o));
    bly = fminf(bly, __shfl_xor(bly, o)); bhy = fmaxf(bhy, __shfl_xor(bhy, o));
    blz = fminf(blz, __shfl_xor(blz, o)); bhz = fmaxf(bhz, __shfl_xor(bhz, o));
  }
  const int cblx = cell1(blx), cbhx = cell1(bhx);
  const int cbly = cell1(bly), cbhy = cell1(bhy);
  const int cblz = cell1(blz), cbhz = cell1(bhz);

  float dist[KNN];
  int idx[KNN];
#pragma unroll
  for (int j = 0; j < KNN; ++j) { dist[j] = __builtin_inff(); idx[j] = 0; }
  float dmax = __builtin_inff();
  int pc = 0;

  int plox = 0, phix = -1, ploy = 0, phiy = -1, ploz = 0, phiz = -1;

  for (int r = 0; r < G; ++r) {
    const int lox = max(cblx - r, 0), hix = min(cbhx + r, G - 1);
    const int loy = max(cbly - r, 0), hiy = min(cbhy + r, G - 1);
    const int loz = max(cblz - r, 0), hiz = min(cbhz + r, G - 1);
    const int nx = hix - lox + 1, ny = hiy - loy + 1, nz = hiz - loz + 1;
    const int vol = nx * ny * nz;

    float wmax = dmax;
#pragma unroll
    for (int o = 1; o < 64; o <<= 1) wmax = fmaxf(wmax, __shfl_xor(wmax, o));

    for (int base = 0; base < vol; base += 64) {
      int k = base + lane;
      int kcx = 0, kcy = 0, kcz = 0, cnt = 0, cst = 0;
      if (k < vol) {
        int tmp = k;
        kcx = lox + tmp % nx; tmp /= nx;
        kcy = loy + tmp % ny; kcz = loz + tmp / ny;
        bool inner = (r > 0) && kcx >= plox && kcx <= phix && kcy >= ploy &&
                     kcy <= phiy && kcz >= ploz && kcz <= phiz;
        if (!inner) {
          int cell = morton3(kcx, kcy, kcz);
          cnt = hist[b * NC + cell];
          if (cnt > 0) {
            // conservative box->cell distance triage (edge cells unbounded)
            float clo = GLO + kcx * WC, chi = clo + WC;
            float dxl = (kcx == 0) ? 0.f : (clo - bhx), dxr = (kcx == G - 1) ? 0.f : (blx - chi);
            float dx = fmaxf(0.f, fmaxf(dxl, dxr));
            clo = GLO + kcy * WC; chi = clo + WC;
            float dyl = (kcy == 0) ? 0.f : (clo - bhy), dyr = (kcy == G - 1) ? 0.f : (bly - chi);
            float dy = fmaxf(0.f, fmaxf(dyl, dyr));
            clo = GLO + kcz * WC; chi = clo + WC;
            float dzl = (kcz == 0) ? 0.f : (clo - bhz), dzr = (kcz == G - 1) ? 0.f : (blz - chi);
            float dz = fmaxf(0.f, fmaxf(dzl, dzr));
            float md = dx * dx + dy * dy + dz * dz;
            if (md <= wmax + EPS) cst = offs[b * NC + cell];
            else cnt = 0;
          }
        }
      }
      unsigned long long mask = __ballot(cnt > 0);
      while (mask) {
        int src = (int)__ffsll(mask) - 1;
        mask &= mask - 1;
        int ccx = __shfl(kcx, src), ccy = __shfl(kcy, src), ccz = __shfl(kcz, src);
        int ccnt = __shfl(cnt, src), ccst = __shfl(cst, src);
        // per-lane exact vote (edge cells unbounded)
        float clo = GLO + ccx * WC, chi = clo + WC;
        float dx = fmaxf(0.f, fmaxf((ccx == 0) ? 0.f : (clo - qd.x),
                                    (ccx == G - 1) ? 0.f : (qd.x - chi)));
        clo = GLO + ccy * WC; chi = clo + WC;
        float dy = fmaxf(0.f, fmaxf((ccy == 0) ? 0.f : (clo - qd.y),
                                    (ccy == G - 1) ? 0.f : (qd.y - chi)));
        clo = GLO + ccz * WC; chi = clo + WC;
        float dz = fmaxf(0.f, fmaxf((ccz == 0) ? 0.f : (clo - qd.z),
                                    (ccz == G - 1) ? 0.f : (qd.z - chi)));
        float md = dx * dx + dy * dy + dz * dz;
        if (!__any(md <= dmax + EPS)) continue;
        int cen = ccst + ccnt;
        for (int p = ccst; p < cen; p += 4) {
          int p1 = min(p + 1, cen - 1), p2 = min(p + 2, cen - 1), p3 = min(p + 3, cen - 1);
          float4 c0 = scand[bbase + p];  int i0 = sidx[bbase + p];
          float4 c1 = scand[bbase + p1]; int i1 = sidx[bbase + p1];
          float4 c2 = scand[bbase + p2]; int i2 = sidx[bbase + p2];
          float4 c3 = scand[bbase + p3]; int i3 = sidx[bbase + p3];
#define PROC(cc, ii, vv)                                              \
          do {                                                        \
            float p0_ = qd.x * (cc).x;                                \
            float dot_ = fmaf(qd.z, (cc).z, fmaf(qd.y, (cc).y, p0_)); \
            float d2_ = fmaf(-2.0f, dot_, qd.w + (cc).w);             \
            if ((vv) && d2_ <= dmax) {                                \
              stk[pc][lane] = make_float2(d2_, __int_as_float(ii));   \
              ++pc;                                                   \
            }                                                         \
          } while (0)
          PROC(c0, i0, true);
          PROC(c1, i1, p + 1 < cen);
          PROC(c2, i2, p + 2 < cen);
          PROC(c3, i3, p + 3 < cen);
#undef PROC
          if (__any(pc >= SDEPTH - 3)) FLUSH();
        }
      }
    }
    FLUSH();
    // stop rule: distance from q to nearest UNVISITED region (grid-edge sides
    // have no unvisited cells -> +inf)
    float margin = 1e30f;
    if (lox > 0)     margin = fminf(margin, qd.x - (GLO + lox * WC));
    if (hix < G - 1) margin = fminf(margin, (GLO + (hix + 1) * WC) - qd.x);
    if (loy > 0)     margin = fminf(margin, qd.y - (GLO + loy * WC));
    if (hiy < G - 1) margin = fminf(margin, (GLO + (hiy + 1) * WC) - qd.y);
    if (loz > 0)     margin = fminf(margin, qd.z - (GLO + loz * WC));
    if (hiz < G - 1) margin = fminf(margin, (GLO + (hiz + 1) * WC) - qd.z);
    bool done = (margin * margin > dmax + EPS);
    if (__all(done)) break;
    plox = lox; phix = hix; ploy = loy; phiy = hiy; ploz = loz; phiz = hiz;
  }

  int* kn = knnt + (size_t)(bbase + orig) * KNN;
#pragma unroll
  for (int j = 0; j < KNN; ++j) kn[j] = idx[j];
}

__global__ void walk_kernel(const int* __restrict__ rand_k, const int* __restrict__ knnt,
                            int* __restrict__ out) {
  int t = blockIdx.x * blockDim.x + threadIdx.x;
  if (t >= NB * NP) return;
  int b = t >> 13;
  int n = t & (NP - 1);
  int cur = n;
  int* o = out + t * CLEN;
  o[0] = cur;
#pragma unroll
  for (int l = 0; l < CLEN - 1; ++l) {
    int rk = rand_k[(l * NB + b) * NP + n];
    cur = knnt[(b * NP + cur) * KNN + rk];
    o[l + 1] = cur;
  }
}

extern "C" void kernel_launch(void* const* d_in, const int* in_sizes, int n_in,
                              void* d_out, int out_size, void* d_ws, size_t ws_size,
                              hipStream_t stream) {
  const float* xyz = (const float*)d_in[0];
  const int* rand_k = (const int*)d_in[1];
  int* out = (int*)d_out;

  char* w = (char*)d_ws;
  float4* scand = (float4*)(w);                       // 512 KB
  int* sidx     = (int*)(w + 524288);                 // 128 KB
  int* knnt     = (int*)(w + 655360);                 // 2 MB
  int* cellid   = (int*)(w + 2752512);                // 128 KB
  int* hist     = (int*)(w + 2883584);                // 64 KB
  int* cursor   = (int*)(w + 2949120);                // 64 KB (adjacent to hist)
  int* offs     = (int*)(w + 3014656);                // 64 KB

  hipMemsetAsync(hist, 0, 131072, stream);  // hist + cursor

  bin_kernel<<<(NB * NP + 255) / 256, 256, 0, stream>>>(xyz, cellid, hist);
  scan_kernel<<<NB, 1024, 0, stream>>>(hist, offs);
  scatter_kernel<<<(NB * NP + 255) / 256, 256, 0, stream>>>(xyz, cellid, offs, cursor,
                                                            scand, sidx);
  knnq_kernel<<<NWAVE, 64, 0, stream>>>(scand, sidx, offs, hist, knnt);
  walk_kernel<<<(NB * NP + 255) / 256, 256, 0, stream>>>(rand_k, knnt, out);
}

// Round 6
// 872.789 us; speedup vs baseline: 1.6727x; 1.6727x over previous
//
#include <hip/hip_runtime.h>
#include <stdint.h>

#define KNN 16
#define CLEN 4
#define NB 4
#define NP 8192
#define G 16
#define NC (G * G * G)
#define GLO -4.5f
#define WC 0.5625f
#define INVW 1.7777777777777777f
#define EPS 1e-3f
#define SDEPTH 12
#define NGRP ((NB * NP) / 64)   // 512 query groups
#define CSPL 8                  // waves per group
#define TPB2 (64 * CSPL)        // 512

// FP-rounding sequence verified bit-exact vs reference (rounds 1-5):
//   sq = (x*x + y*y) + z*z (no fma), dot = fma chain, d2 = fma(-2,dot,sqn+sqm)

__device__ __forceinline__ unsigned sp3(unsigned v) {
  v = (v | (v << 16)) & 0x030000FFu;
  v = (v | (v << 8)) & 0x0300F00Fu;
  v = (v | (v << 4)) & 0x030C30C3u;
  v = (v | (v << 2)) & 0x09249249u;
  return v;
}
__device__ __forceinline__ int morton3(int cx, int cy, int cz) {
  return (int)(sp3((unsigned)cx) | (sp3((unsigned)cy) << 1) | (sp3((unsigned)cz) << 2));
}
__device__ __forceinline__ int cell1(float v) {
  int c = (int)floorf((v - GLO) * INVW);
  return min(G - 1, max(0, c));
}

__global__ void bin_kernel(const float* __restrict__ xyz, int* __restrict__ cellid,
                           int* __restrict__ hist) {
  int t = blockIdx.x * blockDim.x + threadIdx.x;
  if (t >= NB * NP) return;
  int b = t >> 13;
  int m = morton3(cell1(xyz[t * 3 + 0]), cell1(xyz[t * 3 + 1]), cell1(xyz[t * 3 + 2]));
  cellid[t] = m;
  atomicAdd(&hist[b * NC + m], 1);
}

__global__ __launch_bounds__(1024) void scan_kernel(const int* __restrict__ hist,
                                                    int* __restrict__ offs) {
  __shared__ int s[1024];
  int b = blockIdx.x, t = threadIdx.x;
  int base = b * NC + t * 4;
  int v0 = hist[base + 0], v1 = hist[base + 1], v2 = hist[base + 2], v3 = hist[base + 3];
  int sum = v0 + v1 + v2 + v3;
  s[t] = sum;
  __syncthreads();
  for (int d = 1; d < 1024; d <<= 1) {
    int x = 0;
    if (t >= d) x = s[t - d];
    __syncthreads();
    if (t >= d) s[t] += x;
    __syncthreads();
  }
  int run = s[t] - sum;  // exclusive
  offs[base + 0] = run; run += v0;
  offs[base + 1] = run; run += v1;
  offs[base + 2] = run; run += v2;
  offs[base + 3] = run;
}

__global__ void scatter_kernel(const float* __restrict__ xyz, const int* __restrict__ cellid,
                               const int* __restrict__ offs, int* __restrict__ cursor,
                               float4* __restrict__ scand, int* __restrict__ sidx) {
#pragma clang fp contract(off)
  int t = blockIdx.x * blockDim.x + threadIdx.x;
  if (t >= NB * NP) return;
  int b = t >> 13, n = t & (NP - 1);
  float x = xyz[t * 3 + 0], y = xyz[t * 3 + 1], z = xyz[t * 3 + 2];
  float sq = (x * x + y * y) + z * z;   // verified non-fma sequence
  int m = cellid[t];
  int pos = offs[b * NC + m] + atomicAdd(&cursor[b * NC + m], 1);
  scand[b * NP + pos] = make_float4(x, y, z, sq);
  sidx[b * NP + pos] = n;
}

// Lex-stable sorted insert by (d, idx) ascending — exact jax.lax.top_k order.
#define INSERT(dv, iv)                                                        \
  do {                                                                        \
    float _d = (dv); int _i = (iv);                                           \
    bool cl[KNN];                                                             \
    _Pragma("unroll")                                                         \
    for (int j = 0; j < KNN; ++j)                                             \
      cl[j] = (dist[j] > _d) || ((dist[j] == _d) && (idx[j] > _i));           \
    _Pragma("unroll")                                                         \
    for (int j = KNN - 1; j >= 1; --j) {                                      \
      dist[j] = __builtin_amdgcn_fmed3f(dist[j - 1], dist[j], _d);            \
      idx[j] = cl[j - 1] ? idx[j - 1] : (cl[j] ? _i : idx[j]);                \
    }                                                                         \
    dist[0] = fminf(dist[0], _d);                                             \
    idx[0] = cl[0] ? _i : idx[0];                                             \
  } while (0)

#define FLUSH()                                                 \
  do {                                                          \
    float2 e[SDEPTH];                                           \
    _Pragma("unroll")                                           \
    for (int j = 0; j < SDEPTH; ++j) e[j] = stk[j * TPB2 + t];  \
    _Pragma("unroll")                                           \
    for (int j = 0; j < SDEPTH; ++j) {                          \
      if (!__any(j < pc)) break;                                \
      bool act = j < pc;                                        \
      float fd = act ? e[j].x : __builtin_inff();               \
      int fi = __float_as_int(e[j].y);                          \
      INSERT(fd, fi);                                           \
    }                                                           \
    pc = 0;                                                     \
    dmax = dist[KNN - 1];                                       \
  } while (0)

__global__ __launch_bounds__(TPB2, 4) void knnq2_kernel(const float4* __restrict__ scand,
                                                        const int* __restrict__ sidx,
                                                        const int* __restrict__ offs,
                                                        const int* __restrict__ hist,
                                                        int* __restrict__ knnt) {
#pragma clang fp contract(off)
  __shared__ __align__(16) char smem[65536];
  float2* stk = (float2*)smem;  // phase 1: [SDEPTH][TPB2] = 48 KB

  const int t = threadIdx.x;
  const int lane = t & 63;
  const int wid = t >> 6;
  const int wq = blockIdx.x * 64 + lane;  // sorted slot (same 64 queries in all 8 waves)
  const int b = wq >> 13;
  const int bbase = b * NP;
  const float4 qd = scand[wq];
  const int orig = sidx[wq];

  // --- seed with 16 Morton-sorted neighbors (clamped window within batch) ---
  int s0 = wq - 8;
  if (s0 < bbase) s0 = bbase;
  if (s0 > bbase + NP - 16) s0 = bbase + NP - 16;
  const int s0r = s0 - bbase;  // batch-relative skip window start

  float dist[KNN];
  int idx[KNN];
#pragma unroll
  for (int j = 0; j < KNN; ++j) { dist[j] = __builtin_inff(); idx[j] = 0; }
#pragma unroll 1
  for (int i = 0; i < 16; ++i) {
    float4 c = scand[s0 + i];
    int ii = sidx[s0 + i];
    float p0_ = qd.x * c.x;
    float dot_ = fmaf(qd.z, c.z, fmaf(qd.y, c.y, p0_));
    float d2_ = fmaf(-2.0f, dot_, qd.w + c.w);
    INSERT(d2_, ii);
  }
  float dmax = dist[KNN - 1];
  int pc = 0;

  // --- wave bbox of queries + block-uniform selection radius ---
  float blx = qd.x, bhx = qd.x, bly = qd.y, bhy = qd.y, blz = qd.z, bhz = qd.z;
  float rsel2 = dmax;
#pragma unroll
  for (int o = 1; o < 64; o <<= 1) {
    blx = fminf(blx, __shfl_xor(blx, o)); bhx = fmaxf(bhx, __shfl_xor(bhx, o));
    bly = fminf(bly, __shfl_xor(bly, o)); bhy = fmaxf(bhy, __shfl_xor(bhy, o));
    blz = fminf(blz, __shfl_xor(blz, o)); bhz = fmaxf(bhz, __shfl_xor(bhz, o));
    rsel2 = fmaxf(rsel2, __shfl_xor(rsel2, o));
  }
  rsel2 += EPS;                           // squared-space slack (verified scale)
  const float rlin = sqrtf(rsel2) + 1e-3f;

  const int lox = cell1(blx - rlin), hix = cell1(bhx + rlin);
  const int loy = cell1(bly - rlin), hiy = cell1(bhy + rlin);
  const int loz = cell1(blz - rlin), hiz = cell1(bhz + rlin);
  const int nx = hix - lox + 1, ny = hiy - loy + 1, nz = hiz - loz + 1;
  const int vol = nx * ny * nz;

  int ord = 0;  // survivor ordinal (identical across all 8 waves)
  for (int base = 0; base < vol; base += 64) {
    int k = base + lane;
    int kcx = 0, kcy = 0, kcz = 0, cnt = 0, cst = 0;
    if (k < vol) {
      int tmp = k;
      kcx = lox + tmp % nx; tmp /= nx;
      kcy = loy + tmp % ny; kcz = loz + tmp / ny;
      int cell = morton3(kcx, kcy, kcz);
      cnt = hist[b * NC + cell];
      if (cnt > 0) {
        // conservative bbox->cell distance (edge cells unbounded) vs rsel2:
        // block-uniform inputs only -> identical masks in all 8 waves
        float clo = GLO + kcx * WC, chi = clo + WC;
        float dxl = (kcx == 0) ? 0.f : (clo - bhx), dxr = (kcx == G - 1) ? 0.f : (blx - chi);
        float dx = fmaxf(0.f, fmaxf(dxl, dxr));
        clo = GLO + kcy * WC; chi = clo + WC;
        float dyl = (kcy == 0) ? 0.f : (clo - bhy), dyr = (kcy == G - 1) ? 0.f : (bly - chi);
        float dy = fmaxf(0.f, fmaxf(dyl, dyr));
        clo = GLO + kcz * WC; chi = clo + WC;
        float dzl = (kcz == 0) ? 0.f : (clo - bhz), dzr = (kcz == G - 1) ? 0.f : (blz - chi);
        float dz = fmaxf(0.f, fmaxf(dzl, dzr));
        float md = dx * dx + dy * dy + dz * dz;
        if (md <= rsel2) cst = offs[b * NC + cell];
        else cnt = 0;
      }
    }
    unsigned long long mask = __ballot(cnt > 0);
    while (mask) {
      int src = (int)__ffsll(mask) - 1;
      mask &= mask - 1;
      bool take = (ord & (CSPL - 1)) == wid;
      ++ord;
      if (!take) continue;
      int ccx = __shfl(kcx, src), ccy = __shfl(kcy, src), ccz = __shfl(kcz, src);
      int ccnt = __shfl(cnt, src), ccst = __shfl(cst, src);
      // per-lane exact triage vs current (monotone-shrinking, conservative) dmax
      float clo = GLO + ccx * WC, chi = clo + WC;
      float dx = fmaxf(0.f, fmaxf((ccx == 0) ? 0.f : (clo - qd.x),
                                  (ccx == G - 1) ? 0.f : (qd.x - chi)));
      clo = GLO + ccy * WC; chi = clo + WC;
      float dy = fmaxf(0.f, fmaxf((ccy == 0) ? 0.f : (clo - qd.y),
                                  (ccy == G - 1) ? 0.f : (qd.y - chi)));
      clo = GLO + ccz * WC; chi = clo + WC;
      float dz = fmaxf(0.f, fmaxf((ccz == 0) ? 0.f : (clo - qd.z),
                                  (ccz == G - 1) ? 0.f : (qd.z - chi)));
      float md = dx * dx + dy * dy + dz * dz;
      if (!__any(md <= dmax + EPS)) continue;
      int cen = ccst + ccnt;
      for (int p = ccst; p < cen; p += 4) {
        int p1 = min(p + 1, cen - 1), p2 = min(p + 2, cen - 1), p3 = min(p + 3, cen - 1);
        float4 c0 = scand[bbase + p];  int i0 = sidx[bbase + p];
        float4 c1 = scand[bbase + p1]; int i1 = sidx[bbase + p1];
        float4 c2 = scand[bbase + p2]; int i2 = sidx[bbase + p2];
        float4 c3 = scand[bbase + p3]; int i3 = sidx[bbase + p3];
#define PROC(cc, ii, pp, vv)                                          \
        do {                                                          \
          float p0_ = qd.x * (cc).x;                                  \
          float dot_ = fmaf(qd.z, (cc).z, fmaf(qd.y, (cc).y, p0_));   \
          float d2_ = fmaf(-2.0f, dot_, qd.w + (cc).w);               \
          bool w_ = (pp) < s0r || (pp) >= s0r + 16; /* seeds excluded */ \
          if ((vv) && w_ && d2_ <= dmax) {                            \
            stk[pc * TPB2 + t] = make_float2(d2_, __int_as_float(ii)); \
            ++pc;                                                     \
          }                                                           \
        } while (0)
        PROC(c0, i0, p, true);
        PROC(c1, i1, p1, p + 1 < cen);
        PROC(c2, i2, p2, p + 2 < cen);
        PROC(c3, i3, p3, p + 3 < cen);
#undef PROC
        if (__any(pc >= SDEPTH - 3)) FLUSH();
      }
    }
  }
  FLUSH();

  // --- publish per-wave lists (transposed, conflict-free) and dedup-merge ---
  __syncthreads();
  float2* tl = (float2*)smem;  // [KNN][TPB2] = 64 KB
#pragma unroll
  for (int j = 0; j < KNN; ++j)
    tl[j * TPB2 + t] = make_float2(dist[j], __int_as_float(idx[j]));
  __syncthreads();

  if (t < 64) {
    int p[CSPL];
#pragma unroll
    for (int c = 0; c < CSPL; ++c) p[c] = 0;
    int* kn = knnt + (size_t)(bbase + orig) * KNN;  // wave 0: orig is this query's
#pragma unroll 1
    for (int j = 0; j < KNN; ++j) {
      float hd[CSPL];
      int hi[CSPL];
      bool hv[CSPL];
#pragma unroll
      for (int c = 0; c < CSPL; ++c) {
        hv[c] = p[c] < KNN;
        int pp = hv[c] ? p[c] : 0;
        float2 e = tl[pp * TPB2 + c * 64 + t];
        hd[c] = hv[c] ? e.x : __builtin_inff();
        hi[c] = __float_as_int(e.y);
      }
      float bd = hd[0];
      int bi = hi[0];
#pragma unroll
      for (int c = 1; c < CSPL; ++c) {
        bool lt = (hd[c] < bd) || ((hd[c] == bd) && (hi[c] < bi));
        bd = lt ? hd[c] : bd;
        bi = lt ? hi[c] : bi;
      }
      kn[j] = bi;
      // dedup advance: every list whose head equals the emitted (d,idx) moves on
#pragma unroll
      for (int c = 0; c < CSPL; ++c)
        p[c] += (hv[c] && hd[c] == bd && hi[c] == bi) ? 1 : 0;
    }
  }
}

__global__ void walk_kernel(const int* __restrict__ rand_k, const int* __restrict__ knnt,
                            int* __restrict__ out) {
  int t = blockIdx.x * blockDim.x + threadIdx.x;
  if (t >= NB * NP) return;
  int b = t >> 13;
  int n = t & (NP - 1);
  int cur = n;
  int* o = out + t * CLEN;
  o[0] = cur;
#pragma unroll
  for (int l = 0; l < CLEN - 1; ++l) {
    int rk = rand_k[(l * NB + b) * NP + n];
    cur = knnt[(b * NP + cur) * KNN + rk];
    o[l + 1] = cur;
  }
}

extern "C" void kernel_launch(void* const* d_in, const int* in_sizes, int n_in,
                              void* d_out, int out_size, void* d_ws, size_t ws_size,
                              hipStream_t stream) {
  const float* xyz = (const float*)d_in[0];
  const int* rand_k = (const int*)d_in[1];
  int* out = (int*)d_out;

  char* w = (char*)d_ws;
  float4* scand = (float4*)(w);                       // 512 KB
  int* sidx     = (int*)(w + 524288);                 // 128 KB
  int* knnt     = (int*)(w + 655360);                 // 2 MB
  int* cellid   = (int*)(w + 2752512);                // 128 KB
  int* hist     = (int*)(w + 2883584);                // 64 KB
  int* cursor   = (int*)(w + 2949120);                // 64 KB (adjacent to hist)
  int* offs     = (int*)(w + 3014656);                // 64 KB

  hipMemsetAsync(hist, 0, 131072, stream);  // hist + cursor

  bin_kernel<<<(NB * NP + 255) / 256, 256, 0, stream>>>(xyz, cellid, hist);
  scan_kernel<<<NB, 1024, 0, stream>>>(hist, offs);
  scatter_kernel<<<(NB * NP + 255) / 256, 256, 0, stream>>>(xyz, cellid, offs, cursor,
                                                            scand, sidx);
  knnq2_kernel<<<NGRP, TPB2, 0, stream>>>(scand, sidx, offs, hist, knnt);
  walk_kernel<<<(NB * NP + 255) / 256, 256, 0, stream>>>(rand_k, knnt, out);
}

// Round 7
// 670.019 us; speedup vs baseline: 2.1790x; 1.3026x over previous
//
#include <hip/hip_runtime.h>
#include <stdint.h>

#define KNN 16
#define CLEN 4
#define NB 4
#define NP 8192
#define G 16
#define NC (G * G * G)
#define GLO -4.5f
#define INVW 1.7777777777777777f
#define CSPLIT 8
#define CHUNK (NP / CSPLIT)   // 1024 candidates per chunk-thread
#define QPB 64                // queries per block
#define TPB (QPB * CSPLIT)    // 512 threads
#define SDEPTH 16             // per-lane LDS pending stack depth

// FP-rounding sequence verified bit-exact vs reference (rounds 1-6):
//   sq = (x*x + y*y) + z*z (no fma), dot = fma chain, d2 = fma(-2,dot,sqn+sqm)

__device__ __forceinline__ unsigned sp3(unsigned v) {
  v = (v | (v << 16)) & 0x030000FFu;
  v = (v | (v << 8)) & 0x0300F00Fu;
  v = (v | (v << 4)) & 0x030C30C3u;
  v = (v | (v << 2)) & 0x09249249u;
  return v;
}
__device__ __forceinline__ int morton3(int cx, int cy, int cz) {
  return (int)(sp3((unsigned)cx) | (sp3((unsigned)cy) << 1) | (sp3((unsigned)cz) << 2));
}
__device__ __forceinline__ int cell1(float v) {
  int c = (int)floorf((v - GLO) * INVW);
  return min(G - 1, max(0, c));
}

__global__ void bin_kernel(const float* __restrict__ xyz, int* __restrict__ cellid,
                           int* __restrict__ hist) {
  int t = blockIdx.x * blockDim.x + threadIdx.x;
  if (t >= NB * NP) return;
  int b = t >> 13;
  int m = morton3(cell1(xyz[t * 3 + 0]), cell1(xyz[t * 3 + 1]), cell1(xyz[t * 3 + 2]));
  cellid[t] = m;
  atomicAdd(&hist[b * NC + m], 1);
}

__global__ __launch_bounds__(1024) void scan_kernel(const int* __restrict__ hist,
                                                    int* __restrict__ offs) {
  __shared__ int s[1024];
  int b = blockIdx.x, t = threadIdx.x;
  int base = b * NC + t * 4;
  int v0 = hist[base + 0], v1 = hist[base + 1], v2 = hist[base + 2], v3 = hist[base + 3];
  int sum = v0 + v1 + v2 + v3;
  s[t] = sum;
  __syncthreads();
  for (int d = 1; d < 1024; d <<= 1) {
    int x = 0;
    if (t >= d) x = s[t - d];
    __syncthreads();
    if (t >= d) s[t] += x;
    __syncthreads();
  }
  int run = s[t] - sum;  // exclusive
  offs[base + 0] = run; run += v0;
  offs[base + 1] = run; run += v1;
  offs[base + 2] = run; run += v2;
  offs[base + 3] = run;
}

__global__ void scatter_kernel(const float* __restrict__ xyz, const int* __restrict__ cellid,
                               const int* __restrict__ offs, int* __restrict__ cursor,
                               float4* __restrict__ scand, int* __restrict__ sidx) {
#pragma clang fp contract(off)
  int t = blockIdx.x * blockDim.x + threadIdx.x;
  if (t >= NB * NP) return;
  int b = t >> 13, n = t & (NP - 1);
  float x = xyz[t * 3 + 0], y = xyz[t * 3 + 1], z = xyz[t * 3 + 2];
  float sq = (x * x + y * y) + z * z;   // verified non-fma sequence
  int m = cellid[t];
  int pos = offs[b * NC + m] + atomicAdd(&cursor[b * NC + m], 1);
  scand[b * NP + pos] = make_float4(x, y, z, sq);
  sidx[b * NP + pos] = n;
}

// Lex-stable sorted insert by (d, idx) ascending — exact jax.lax.top_k order.
// Verified bit-exact in rounds 5-6.
#define INSERT(dv, iv)                                                        \
  do {                                                                        \
    float _d = (dv); int _i = (iv);                                           \
    bool cl[KNN];                                                             \
    _Pragma("unroll")                                                         \
    for (int j = 0; j < KNN; ++j)                                             \
      cl[j] = (dist[j] > _d) || ((dist[j] == _d) && (idx[j] > _i));           \
    _Pragma("unroll")                                                         \
    for (int j = KNN - 1; j >= 1; --j) {                                      \
      dist[j] = __builtin_amdgcn_fmed3f(dist[j - 1], dist[j], _d);            \
      idx[j] = cl[j - 1] ? idx[j - 1] : (cl[j] ? _i : idx[j]);                \
    }                                                                         \
    dist[0] = fminf(dist[0], _d);                                             \
    idx[0] = cl[0] ? _i : idx[0];                                             \
  } while (0)

// Batched drain, oldest first. Safe vs garbage slots (j >= pc): fd = +inf is a
// no-op for a list that is already full of finite seeds (always true here).
#define FLUSH()                                                 \
  do {                                                          \
    float2 e[SDEPTH];                                           \
    _Pragma("unroll")                                           \
    for (int j = 0; j < SDEPTH; ++j) e[j] = stk[j * TPB + t];   \
    _Pragma("unroll")                                           \
    for (int j = 0; j < SDEPTH; ++j) {                          \
      if (!__any(j < pc)) break;                                \
      bool act = j < pc;                                        \
      float fd = act ? e[j].x : __builtin_inff();               \
      int fi = __float_as_int(e[j].y);                          \
      INSERT(fd, fi);                                           \
    }                                                           \
    pc = 0;                                                     \
    dmax = dist[KNN - 1];                                       \
  } while (0)

__global__ __launch_bounds__(TPB, 4) void knns_kernel(const float4* __restrict__ scand,
                                                      const int* __restrict__ sidx,
                                                      int* __restrict__ knnt) {
#pragma clang fp contract(off)
  // 64 KB shared, aliased: phase 1 stacks [SDEPTH][TPB] f2, phase 2 merge [KNN][TPB] f2
  __shared__ __align__(16) char smem[65536];
  float2* stk = (float2*)smem;

  const int t = threadIdx.x;
  const int q_local = t & (QPB - 1);
  const int chunk = t >> 6;
  const int wq = blockIdx.x * QPB + q_local;  // sorted slot
  const int b = wq >> 13;
  const int bbase = b * NP;
  const float4 qd = scand[wq];
  const int orig = sidx[wq];
  const float4* cb = scand + bbase;

  // --- seed with 16 Morton-window neighbors (includes self; clamped) ---
  int s0 = wq - 8;
  if (s0 < bbase) s0 = bbase;
  if (s0 > bbase + NP - 16) s0 = bbase + NP - 16;
  const int s0r = s0 - bbase;  // batch-relative window start

  float dist[KNN];
  int idx[KNN];
#pragma unroll
  for (int j = 0; j < KNN; ++j) { dist[j] = __builtin_inff(); idx[j] = 0; }
#pragma unroll 1
  for (int i = 0; i < 16; i += 4) {
    float4 c0 = scand[s0 + i + 0]; int i0 = sidx[s0 + i + 0];
    float4 c1 = scand[s0 + i + 1]; int i1 = sidx[s0 + i + 1];
    float4 c2 = scand[s0 + i + 2]; int i2 = sidx[s0 + i + 2];
    float4 c3 = scand[s0 + i + 3]; int i3 = sidx[s0 + i + 3];
#define SEED(cc, ii)                                               \
    do {                                                           \
      float p0_ = qd.x * (cc).x;                                   \
      float dot_ = fmaf(qd.z, (cc).z, fmaf(qd.y, (cc).y, p0_));    \
      float d2_ = fmaf(-2.0f, dot_, qd.w + (cc).w);                \
      INSERT(d2_, (ii));                                           \
    } while (0)
    SEED(c0, i0); SEED(c1, i1); SEED(c2, i2); SEED(c3, i3);
#undef SEED
  }
  float dmax = dist[KNN - 1];
  int pc = 0;

  // --- exhaustive scan of this chunk's slice, seeds excluded by position ---
  const int m0 = chunk * CHUNK;
  for (int s = 0; s < CHUNK; s += 8) {
    float4 c0 = cb[m0 + s + 0];
    float4 c1 = cb[m0 + s + 1];
    float4 c2 = cb[m0 + s + 2];
    float4 c3 = cb[m0 + s + 3];
    float4 c4 = cb[m0 + s + 4];
    float4 c5 = cb[m0 + s + 5];
    float4 c6 = cb[m0 + s + 6];
    float4 c7 = cb[m0 + s + 7];
#define PROC(cc, mm)                                                  \
    do {                                                              \
      float p0_ = qd.x * (cc).x;                                      \
      float dot_ = fmaf(qd.z, (cc).z, fmaf(qd.y, (cc).y, p0_));       \
      float d2_ = fmaf(-2.0f, dot_, qd.w + (cc).w);                   \
      if ((unsigned)((mm) - s0r) >= 16u && d2_ <= dmax) {             \
        int ii_ = sidx[bbase + (mm)]; /* wave-uniform broadcast */    \
        stk[pc * TPB + t] = make_float2(d2_, __int_as_float(ii_));    \
        ++pc;                                                         \
      }                                                               \
    } while (0)
    PROC(c0, m0 + s + 0);
    PROC(c1, m0 + s + 1);
    PROC(c2, m0 + s + 2);
    PROC(c3, m0 + s + 3);
    PROC(c4, m0 + s + 4);
    PROC(c5, m0 + s + 5);
    PROC(c6, m0 + s + 6);
    PROC(c7, m0 + s + 7);
#undef PROC
    // post-flush pc==0; each 8-group adds <=8; flush at >=9 keeps pc<=SDEPTH
    if (__any(pc >= SDEPTH - 7)) FLUSH();
  }
  FLUSH();

  // --- publish per-chunk lists (transposed, conflict-free) + dedup merge ---
  __syncthreads();
  float2* tl = (float2*)smem;  // [KNN][TPB] = 64 KB
#pragma unroll
  for (int j = 0; j < KNN; ++j)
    tl[j * TPB + t] = make_float2(dist[j], __int_as_float(idx[j]));
  __syncthreads();

  if (t < QPB) {
    int p[CSPLIT];
#pragma unroll
    for (int c = 0; c < CSPLIT; ++c) p[c] = 0;
    int* kn = knnt + (size_t)(bbase + orig) * KNN;
#pragma unroll 1
    for (int j = 0; j < KNN; ++j) {
      float hd[CSPLIT];
      int hi[CSPLIT];
      bool hv[CSPLIT];
#pragma unroll
      for (int c = 0; c < CSPLIT; ++c) {
        hv[c] = p[c] < KNN;
        int pp = hv[c] ? p[c] : 0;
        float2 e = tl[pp * TPB + c * QPB + t];
        hd[c] = hv[c] ? e.x : __builtin_inff();
        hi[c] = __float_as_int(e.y);
      }
      float bd = hd[0];
      int bi = hi[0];
#pragma unroll
      for (int c = 1; c < CSPLIT; ++c) {
        bool lt = (hd[c] < bd) || ((hd[c] == bd) && (hi[c] < bi));
        bd = lt ? hd[c] : bd;
        bi = lt ? hi[c] : bi;
      }
      kn[j] = bi;
      // dedup advance: every list whose head equals the emitted (d,idx) moves on
#pragma unroll
      for (int c = 0; c < CSPLIT; ++c)
        p[c] += (hv[c] && hd[c] == bd && hi[c] == bi) ? 1 : 0;
    }
  }
}

__global__ void walk_kernel(const int* __restrict__ rand_k, const int* __restrict__ knnt,
                            int* __restrict__ out) {
  int t = blockIdx.x * blockDim.x + threadIdx.x;
  if (t >= NB * NP) return;
  int b = t >> 13;
  int n = t & (NP - 1);
  int cur = n;
  int* o = out + t * CLEN;
  o[0] = cur;
#pragma unroll
  for (int l = 0; l < CLEN - 1; ++l) {
    int rk = rand_k[(l * NB + b) * NP + n];
    cur = knnt[(b * NP + cur) * KNN + rk];
    o[l + 1] = cur;
  }
}

extern "C" void kernel_launch(void* const* d_in, const int* in_sizes, int n_in,
                              void* d_out, int out_size, void* d_ws, size_t ws_size,
                              hipStream_t stream) {
  const float* xyz = (const float*)d_in[0];
  const int* rand_k = (const int*)d_in[1];
  int* out = (int*)d_out;

  char* w = (char*)d_ws;
  float4* scand = (float4*)(w);                       // 512 KB
  int* sidx     = (int*)(w + 524288);                 // 128 KB
  int* knnt     = (int*)(w + 655360);                 // 2 MB
  int* cellid   = (int*)(w + 2752512);                // 128 KB
  int* hist     = (int*)(w + 2883584);                // 64 KB
  int* cursor   = (int*)(w + 2949120);                // 64 KB (adjacent to hist)
  int* offs     = (int*)(w + 3014656);                // 64 KB

  hipMemsetAsync(hist, 0, 131072, stream);  // hist + cursor

  bin_kernel<<<(NB * NP + 255) / 256, 256, 0, stream>>>(xyz, cellid, hist);
  scan_kernel<<<NB, 1024, 0, stream>>>(hist, offs);
  scatter_kernel<<<(NB * NP + 255) / 256, 256, 0, stream>>>(xyz, cellid, offs, cursor,
                                                            scand, sidx);
  knns_kernel<<<(NB * NP) / QPB, TPB, 0, stream>>>(scand, sidx, knnt);
  walk_kernel<<<(NB * NP + 255) / 256, 256, 0, stream>>>(rand_k, knnt, out);
}

// Round 8
// 194.205 us; speedup vs baseline: 7.5176x; 3.4501x over previous
//
#include <hip/hip_runtime.h>
#include <stdint.h>

#define KNN 16
#define CLEN 4
#define NB 4
#define NP 8192
#define G 16
#define NC (G * G * G)
#define GLO -4.5f
#define INVW 1.7777777777777777f
#define CSPLIT 8
#define CHUNK (NP / CSPLIT)   // 1024 candidates per chunk-thread
#define QPB 64                // queries per block
#define TPB (QPB * CSPLIT)    // 512 threads
#define SDEPTH 12             // per-lane LDS pending stack depth

// FP-rounding sequence verified bit-exact vs reference (rounds 1-7):
//   sq = (x*x + y*y) + z*z (no fma), dot = fma chain, d2 = fma(-2,dot,sqn+sqm)

__device__ __forceinline__ unsigned sp3(unsigned v) {
  v = (v | (v << 16)) & 0x030000FFu;
  v = (v | (v << 8)) & 0x0300F00Fu;
  v = (v | (v << 4)) & 0x030C30C3u;
  v = (v | (v << 2)) & 0x09249249u;
  return v;
}
__device__ __forceinline__ int morton3(int cx, int cy, int cz) {
  return (int)(sp3((unsigned)cx) | (sp3((unsigned)cy) << 1) | (sp3((unsigned)cz) << 2));
}
__device__ __forceinline__ int cell1(float v) {
  int c = (int)floorf((v - GLO) * INVW);
  return min(G - 1, max(0, c));
}

__global__ void bin_kernel(const float* __restrict__ xyz, int* __restrict__ cellid,
                           int* __restrict__ hist) {
  int t = blockIdx.x * blockDim.x + threadIdx.x;
  if (t >= NB * NP) return;
  int b = t >> 13;
  int m = morton3(cell1(xyz[t * 3 + 0]), cell1(xyz[t * 3 + 1]), cell1(xyz[t * 3 + 2]));
  cellid[t] = m;
  atomicAdd(&hist[b * NC + m], 1);
}

__global__ __launch_bounds__(1024) void scan_kernel(const int* __restrict__ hist,
                                                    int* __restrict__ offs) {
  __shared__ int s[1024];
  int b = blockIdx.x, t = threadIdx.x;
  int base = b * NC + t * 4;
  int v0 = hist[base + 0], v1 = hist[base + 1], v2 = hist[base + 2], v3 = hist[base + 3];
  int sum = v0 + v1 + v2 + v3;
  s[t] = sum;
  __syncthreads();
  for (int d = 1; d < 1024; d <<= 1) {
    int x = 0;
    if (t >= d) x = s[t - d];
    __syncthreads();
    if (t >= d) s[t] += x;
    __syncthreads();
  }
  int run = s[t] - sum;  // exclusive
  offs[base + 0] = run; run += v0;
  offs[base + 1] = run; run += v1;
  offs[base + 2] = run; run += v2;
  offs[base + 3] = run;
}

// Writes BOTH the Morton-sorted array (for threshold windows) and the
// natural-order array (for the balanced brute-force scan).
__global__ void scatter_kernel(const float* __restrict__ xyz, const int* __restrict__ cellid,
                               const int* __restrict__ offs, int* __restrict__ cursor,
                               float4* __restrict__ scand, int* __restrict__ sidx,
                               float4* __restrict__ cand) {
#pragma clang fp contract(off)
  int t = blockIdx.x * blockDim.x + threadIdx.x;
  if (t >= NB * NP) return;
  int b = t >> 13, n = t & (NP - 1);
  float x = xyz[t * 3 + 0], y = xyz[t * 3 + 1], z = xyz[t * 3 + 2];
  float sq = (x * x + y * y) + z * z;   // verified non-fma sequence
  cand[t] = make_float4(x, y, z, sq);
  int m = cellid[t];
  int pos = offs[b * NC + m] + atomicAdd(&cursor[b * NC + m], 1);
  scand[b * NP + pos] = make_float4(x, y, z, sq);
  sidx[b * NP + pos] = n;
}

// Per-query selection threshold = max distance over its 16-point Morton window.
// max(any 16-subset) >= global 16th-smallest  ->  conservative, exact.
__global__ void thresh_kernel(const float4* __restrict__ scand, const int* __restrict__ sidx,
                              float* __restrict__ thr) {
#pragma clang fp contract(off)
  int s = blockIdx.x * blockDim.x + threadIdx.x;
  if (s >= NB * NP) return;
  int b = s >> 13;
  int bbase = b * NP;
  float4 qd = scand[s];
  int w0 = s - 8;
  if (w0 < bbase) w0 = bbase;
  if (w0 > bbase + NP - 16) w0 = bbase + NP - 16;
  float maxd = 0.f;
#pragma unroll
  for (int i = 0; i < 16; ++i) {
    float4 c = scand[w0 + i];
    float p0 = qd.x * c.x;
    float dot = fmaf(qd.z, c.z, fmaf(qd.y, c.y, p0));
    float d2 = fmaf(-2.0f, dot, qd.w + c.w);
    maxd = fmaxf(maxd, d2);
  }
  thr[bbase + sidx[s]] = maxd;
}

// Stable sorted-insert into ascending (dist[], idx[]), med3 encoding
// (verified bit-exact rounds 1-4). Strict > places d after equals; candidates
// arrive in ascending natural index order -> exact top_k tie semantics.
#define INSERT(dv, iv)                                              \
  do {                                                              \
    float _d = (dv); int _i = (iv);                                 \
    bool c[KNN];                                                    \
    _Pragma("unroll")                                               \
    for (int j = 0; j < KNN; ++j) c[j] = dist[j] > _d;              \
    _Pragma("unroll")                                               \
    for (int j = KNN - 1; j >= 1; --j) {                            \
      dist[j] = __builtin_amdgcn_fmed3f(dist[j - 1], dist[j], _d);  \
      idx[j] = c[j - 1] ? idx[j - 1] : (c[j] ? _i : idx[j]);        \
    }                                                               \
    dist[0] = fminf(dist[0], _d);                                   \
    idx[0] = c[0] ? _i : idx[0];                                    \
  } while (0)

// Batched drain, oldest first. dmax tightens but never loosens past the
// seed threshold (list 16th starts at +inf).
#define FLUSH()                                                \
  do {                                                         \
    float2 e[SDEPTH];                                          \
    _Pragma("unroll")                                          \
    for (int j = 0; j < SDEPTH; ++j) e[j] = stk[j * TPB + t];  \
    _Pragma("unroll")                                          \
    for (int j = 0; j < SDEPTH; ++j) {                         \
      if (!__any(j < pc)) break;                               \
      bool act = j < pc;                                       \
      float fd = act ? e[j].x : __builtin_inff();              \
      int fi = __float_as_int(e[j].y);                         \
      INSERT(fd, fi);                                          \
    }                                                          \
    pc = 0;                                                    \
    dmax = fminf(dmax, dist[KNN - 1]);                         \
  } while (0)

__global__ __launch_bounds__(TPB, 4) void knn_kernel(const float4* __restrict__ cand,
                                                     const float* __restrict__ thr,
                                                     int* __restrict__ knn) {
#pragma clang fp contract(off)
  // 48 KB shared, aliased: phase 1 stacks, phase 2 transposed merge lists
  __shared__ __align__(16) char smem[49152];
  float2* stk = (float2*)smem;

  const int t = threadIdx.x;
  const int q_local = t & (QPB - 1);
  const int chunk = t >> 6;
  const int bq = blockIdx.x * QPB + q_local;
  const int b = bq >> 13;
  const float4 qd = cand[bq];
  const float4* cb = cand + b * NP;

  float dist[KNN];
  int idx[KNN];
#pragma unroll
  for (int j = 0; j < KNN; ++j) { dist[j] = __builtin_inff(); idx[j] = 0; }
  float dmax = thr[bq];   // conservative seed threshold (>= true 16th distance)
  int pc = 0;

  const int m0 = chunk * CHUNK;
  for (int s = 0; s < CHUNK; s += 8) {
    float4 c0 = cb[m0 + s + 0];
    float4 c1 = cb[m0 + s + 1];
    float4 c2 = cb[m0 + s + 2];
    float4 c3 = cb[m0 + s + 3];
    float4 c4 = cb[m0 + s + 4];
    float4 c5 = cb[m0 + s + 5];
    float4 c6 = cb[m0 + s + 6];
    float4 c7 = cb[m0 + s + 7];
#define PROC(cc, mm)                                                \
    do {                                                            \
      float p0 = qd.x * (cc).x;                                     \
      float dot = fmaf(qd.z, (cc).z, fmaf(qd.y, (cc).y, p0));       \
      float d2 = fmaf(-2.0f, dot, qd.w + (cc).w);                   \
      if (d2 <= dmax) { /* <= : boundary (seed) points admissible */\
        stk[pc * TPB + t] = make_float2(d2, __int_as_float(mm));    \
        ++pc;                                                       \
      }                                                             \
    } while (0)
    PROC(c0, m0 + s + 0);
    PROC(c1, m0 + s + 1);
    PROC(c2, m0 + s + 2);
    PROC(c3, m0 + s + 3);
    if (__any(pc >= SDEPTH - 3)) FLUSH();
    PROC(c4, m0 + s + 4);
    PROC(c5, m0 + s + 5);
    PROC(c6, m0 + s + 6);
    PROC(c7, m0 + s + 7);
    if (__any(pc >= SDEPTH - 3)) FLUSH();
#undef PROC
  }
  FLUSH();

  __syncthreads();  // repurpose smem: transposed lists (conflict-free)
  float2* tl = (float2*)smem;               // [KNN][4*QPB] = 32 KB
  float2* al = (float2*)(smem + 32768);     // [KNN][QPB]   =  8 KB

  // ---- phase A: chunks 0..3 publish, 4-way stable merge -> al ----
  if (chunk < 4) {
#pragma unroll
    for (int j = 0; j < KNN; ++j)
      tl[j * (4 * QPB) + t] = make_float2(dist[j], __int_as_float(idx[j]));
  }
  __syncthreads();
  if (t < QPB) {
    int p[4] = {0, 0, 0, 0};
#pragma unroll 1
    for (int j = 0; j < KNN; ++j) {
      float bd = __builtin_inff();
      int bi = 0, bc = 0;
#pragma unroll
      for (int c = 0; c < 4; ++c) {
        bool v = p[c] < KNN;
        int pp = v ? p[c] : 0;
        float2 e = tl[pp * (4 * QPB) + t + c * QPB];
        float hd = v ? e.x : __builtin_inff();
        // strict < keeps the earliest chunk on ties (ascending index ranges)
        if (hd < bd || c == 0) { bd = hd; bi = __float_as_int(e.y); bc = c; }
      }
      al[j * QPB + t] = make_float2(bd, __int_as_float(bi));
#pragma unroll
      for (int c = 0; c < 4; ++c) p[c] += (bc == c);
    }
  }
  __syncthreads();

  // ---- phase B: chunks 4..7 publish (reuse region), 5-way merge -> out ----
  if (chunk >= 4) {
#pragma unroll
    for (int j = 0; j < KNN; ++j)
      tl[j * (4 * QPB) + (t - 4 * QPB)] = make_float2(dist[j], __int_as_float(idx[j]));
  }
  __syncthreads();
  if (t < QPB) {
    int p[5] = {0, 0, 0, 0, 0};  // 0 = al (chunks 0-3), 1..4 = chunks 4..7
    int* kn = knn + bq * KNN;
#pragma unroll 1
    for (int j = 0; j < KNN; ++j) {
      float bd;
      int bi, bc;
      {
        bool v = p[0] < KNN;
        int pp = v ? p[0] : 0;
        float2 e = al[pp * QPB + t];
        bd = v ? e.x : __builtin_inff();
        bi = __float_as_int(e.y);
        bc = 0;
      }
#pragma unroll
      for (int c = 0; c < 4; ++c) {
        bool v = p[c + 1] < KNN;
        int pp = v ? p[c + 1] : 0;
        float2 e = tl[pp * (4 * QPB) + t + c * QPB];
        float hd = v ? e.x : __builtin_inff();
        if (hd < bd) { bd = hd; bi = __float_as_int(e.y); bc = c + 1; }
      }
      kn[j] = bi;
#pragma unroll
      for (int c = 0; c < 5; ++c) p[c] += (bc == c);
    }
  }
}

__global__ void walk_kernel(const int* __restrict__ rand_k, const int* __restrict__ knn,
                            int* __restrict__ out) {
  int t = blockIdx.x * blockDim.x + threadIdx.x;
  if (t >= NB * NP) return;
  int b = t >> 13;
  int n = t & (NP - 1);
  int cur = n;
  int* o = out + t * CLEN;
  o[0] = cur;
#pragma unroll
  for (int l = 0; l < CLEN - 1; ++l) {
    int rk = rand_k[(l * NB + b) * NP + n];
    cur = knn[(b * NP + cur) * KNN + rk];
    o[l + 1] = cur;
  }
}

extern "C" void kernel_launch(void* const* d_in, const int* in_sizes, int n_in,
                              void* d_out, int out_size, void* d_ws, size_t ws_size,
                              hipStream_t stream) {
  const float* xyz = (const float*)d_in[0];
  const int* rand_k = (const int*)d_in[1];
  int* out = (int*)d_out;

  char* w = (char*)d_ws;
  float4* cand  = (float4*)(w);                       // 512 KB natural order
  float4* scand = (float4*)(w + 524288);              // 512 KB Morton-sorted
  int* sidx     = (int*)(w + 1048576);                // 128 KB
  float* thr    = (float*)(w + 1179648);              // 128 KB
  int* knnt     = (int*)(w + 1310720);                // 2 MB
  int* cellid   = (int*)(w + 3407872);                // 128 KB
  int* hist     = (int*)(w + 3538944);                // 64 KB
  int* cursor   = (int*)(w + 3604480);                // 64 KB (adjacent)
  int* offs     = (int*)(w + 3670016);                // 64 KB

  hipMemsetAsync(hist, 0, 131072, stream);  // hist + cursor

  bin_kernel<<<(NB * NP + 255) / 256, 256, 0, stream>>>(xyz, cellid, hist);
  scan_kernel<<<NB, 1024, 0, stream>>>(hist, offs);
  scatter_kernel<<<(NB * NP + 255) / 256, 256, 0, stream>>>(xyz, cellid, offs, cursor,
                                                            scand, sidx, cand);
  thresh_kernel<<<(NB * NP + 255) / 256, 256, 0, stream>>>(scand, sidx, thr);
  knn_kernel<<<(NB * NP) / QPB, TPB, 0, stream>>>(cand, thr, knnt);
  walk_kernel<<<(NB * NP + 255) / 256, 256, 0, stream>>>(rand_k, knnt, out);
}

// Round 9
// 172.694 us; speedup vs baseline: 8.4539x; 1.1246x over previous
//
#include <hip/hip_runtime.h>
#include <stdint.h>

#define KNN 16
#define CLEN 4
#define NB 4
#define NP 8192
#define G 16
#define NC (G * G * G)
#define GLO -4.5f
#define INVW 1.7777777777777777f
#define CSPLIT 8
#define CHUNK (NP / CSPLIT)   // 1024 candidates per chunk-thread
#define QPB 64                // queries per block
#define TPB (QPB * CSPLIT)    // 512 threads
#define SDEPTH 12             // per-lane LDS pending stack depth
#define TWIN 48               // threshold window (16th-smallest of 48)

// FP-rounding sequence verified bit-exact vs reference (rounds 1-8):
//   sq = (x*x + y*y) + z*z (no fma), dot = fma chain, d2 = fma(-2,dot,sqn+sqm)

__device__ __forceinline__ unsigned sp3(unsigned v) {
  v = (v | (v << 16)) & 0x030000FFu;
  v = (v | (v << 8)) & 0x0300F00Fu;
  v = (v | (v << 4)) & 0x030C30C3u;
  v = (v | (v << 2)) & 0x09249249u;
  return v;
}
__device__ __forceinline__ int morton3(int cx, int cy, int cz) {
  return (int)(sp3((unsigned)cx) | (sp3((unsigned)cy) << 1) | (sp3((unsigned)cz) << 2));
}
__device__ __forceinline__ int cell1(float v) {
  int c = (int)floorf((v - GLO) * INVW);
  return min(G - 1, max(0, c));
}

__global__ void bin_kernel(const float* __restrict__ xyz, int* __restrict__ cellid,
                           int* __restrict__ hist) {
  int t = blockIdx.x * blockDim.x + threadIdx.x;
  if (t >= NB * NP) return;
  int b = t >> 13;
  int m = morton3(cell1(xyz[t * 3 + 0]), cell1(xyz[t * 3 + 1]), cell1(xyz[t * 3 + 2]));
  cellid[t] = m;
  atomicAdd(&hist[b * NC + m], 1);
}

__global__ __launch_bounds__(1024) void scan_kernel(const int* __restrict__ hist,
                                                    int* __restrict__ offs) {
  __shared__ int s[1024];
  int b = blockIdx.x, t = threadIdx.x;
  int base = b * NC + t * 4;
  int v0 = hist[base + 0], v1 = hist[base + 1], v2 = hist[base + 2], v3 = hist[base + 3];
  int sum = v0 + v1 + v2 + v3;
  s[t] = sum;
  __syncthreads();
  for (int d = 1; d < 1024; d <<= 1) {
    int x = 0;
    if (t >= d) x = s[t - d];
    __syncthreads();
    if (t >= d) s[t] += x;
    __syncthreads();
  }
  int run = s[t] - sum;  // exclusive
  offs[base + 0] = run; run += v0;
  offs[base + 1] = run; run += v1;
  offs[base + 2] = run; run += v2;
  offs[base + 3] = run;
}

// Writes BOTH the Morton-sorted array (for threshold windows) and the
// natural-order array (for the balanced brute-force scan).
__global__ void scatter_kernel(const float* __restrict__ xyz, const int* __restrict__ cellid,
                               const int* __restrict__ offs, int* __restrict__ cursor,
                               float4* __restrict__ scand, int* __restrict__ sidx,
                               float4* __restrict__ cand) {
#pragma clang fp contract(off)
  int t = blockIdx.x * blockDim.x + threadIdx.x;
  if (t >= NB * NP) return;
  int b = t >> 13, n = t & (NP - 1);
  float x = xyz[t * 3 + 0], y = xyz[t * 3 + 1], z = xyz[t * 3 + 2];
  float sq = (x * x + y * y) + z * z;   // verified non-fma sequence
  cand[t] = make_float4(x, y, z, sq);
  int m = cellid[t];
  int pos = offs[b * NC + m] + atomicAdd(&cursor[b * NC + m], 1);
  scand[b * NP + pos] = make_float4(x, y, z, sq);
  sidx[b * NP + pos] = n;
}

// Per-query selection threshold = 16th-SMALLEST distance over a 48-point
// Morton window. 16th-of-any-48-subset >= global 16th-smallest -> exact-
// conservative, and robust to Morton-seam outliers (unlike max-of-16).
__global__ void thresh_kernel(const float4* __restrict__ scand, const int* __restrict__ sidx,
                              float* __restrict__ thr) {
#pragma clang fp contract(off)
  int s = blockIdx.x * blockDim.x + threadIdx.x;
  if (s >= NB * NP) return;
  int b = s >> 13;
  int bbase = b * NP;
  float4 qd = scand[s];
  int w0 = s - (TWIN / 2);
  if (w0 < bbase) w0 = bbase;
  if (w0 > bbase + NP - TWIN) w0 = bbase + NP - TWIN;
  float dist[KNN];
#pragma unroll
  for (int j = 0; j < KNN; ++j) dist[j] = __builtin_inff();
#pragma unroll 1
  for (int i = 0; i < TWIN; i += 8) {
    float4 c0 = scand[w0 + i + 0];
    float4 c1 = scand[w0 + i + 1];
    float4 c2 = scand[w0 + i + 2];
    float4 c3 = scand[w0 + i + 3];
    float4 c4 = scand[w0 + i + 4];
    float4 c5 = scand[w0 + i + 5];
    float4 c6 = scand[w0 + i + 6];
    float4 c7 = scand[w0 + i + 7];
#define TPROC(cc)                                                   \
    do {                                                            \
      float p0 = qd.x * (cc).x;                                     \
      float dot = fmaf(qd.z, (cc).z, fmaf(qd.y, (cc).y, p0));       \
      float d2 = fmaf(-2.0f, dot, qd.w + (cc).w);                   \
      _Pragma("unroll")                                             \
      for (int j = KNN - 1; j >= 1; --j)                            \
        dist[j] = __builtin_amdgcn_fmed3f(dist[j - 1], dist[j], d2);\
      dist[0] = fminf(dist[0], d2);                                 \
    } while (0)
    TPROC(c0); TPROC(c1); TPROC(c2); TPROC(c3);
    TPROC(c4); TPROC(c5); TPROC(c6); TPROC(c7);
#undef TPROC
  }
  thr[bbase + sidx[s]] = dist[KNN - 1];
}

// Stable sorted-insert into ascending (dist[], idx[]), med3 encoding
// (verified bit-exact rounds 1-4, 7-8). Strict > places d after equals;
// candidates arrive in ascending natural index order -> exact top_k ties.
#define INSERT(dv, iv)                                              \
  do {                                                              \
    float _d = (dv); int _i = (iv);                                 \
    bool c[KNN];                                                    \
    _Pragma("unroll")                                               \
    for (int j = 0; j < KNN; ++j) c[j] = dist[j] > _d;              \
    _Pragma("unroll")                                               \
    for (int j = KNN - 1; j >= 1; --j) {                            \
      dist[j] = __builtin_amdgcn_fmed3f(dist[j - 1], dist[j], _d);  \
      idx[j] = c[j - 1] ? idx[j - 1] : (c[j] ? _i : idx[j]);        \
    }                                                               \
    dist[0] = fminf(dist[0], _d);                                   \
    idx[0] = c[0] ? _i : idx[0];                                    \
  } while (0)

// Batched drain, oldest first. dmax tightens but never loosens past the
// seed threshold (list 16th starts at +inf).
#define FLUSH()                                                \
  do {                                                         \
    float2 e[SDEPTH];                                          \
    _Pragma("unroll")                                          \
    for (int j = 0; j < SDEPTH; ++j) e[j] = stk[j * TPB + t];  \
    _Pragma("unroll")                                          \
    for (int j = 0; j < SDEPTH; ++j) {                         \
      if (!__any(j < pc)) break;                               \
      bool act = j < pc;                                       \
      float fd = act ? e[j].x : __builtin_inff();              \
      int fi = __float_as_int(e[j].y);                         \
      INSERT(fd, fi);                                          \
    }                                                          \
    pc = 0;                                                    \
    dmax = fminf(dmax, dist[KNN - 1]);                         \
  } while (0)

__global__ __launch_bounds__(TPB, 4) void knn_kernel(const float4* __restrict__ cand,
                                                     const float* __restrict__ thr,
                                                     int* __restrict__ knn) {
#pragma clang fp contract(off)
  // 48 KB shared, aliased: phase 1 stacks, phase 2 transposed merge lists
  __shared__ __align__(16) char smem[49152];
  float2* stk = (float2*)smem;

  const int t = threadIdx.x;
  const int q_local = t & (QPB - 1);
  const int chunk = t >> 6;
  const int bq = blockIdx.x * QPB + q_local;
  const int b = bq >> 13;
  const float4 qd = cand[bq];
  const float4* cb = cand + b * NP;

  float dist[KNN];
  int idx[KNN];
#pragma unroll
  for (int j = 0; j < KNN; ++j) { dist[j] = __builtin_inff(); idx[j] = 0; }
  float dmax = thr[bq];   // conservative seed threshold (>= true 16th distance)
  int pc = 0;

  const int m0 = chunk * CHUNK;
  for (int s = 0; s < CHUNK; s += 8) {
    float4 c0 = cb[m0 + s + 0];
    float4 c1 = cb[m0 + s + 1];
    float4 c2 = cb[m0 + s + 2];
    float4 c3 = cb[m0 + s + 3];
    float4 c4 = cb[m0 + s + 4];
    float4 c5 = cb[m0 + s + 5];
    float4 c6 = cb[m0 + s + 6];
    float4 c7 = cb[m0 + s + 7];
#define PROC(cc, mm)                                                \
    do {                                                            \
      float p0 = qd.x * (cc).x;                                     \
      float dot = fmaf(qd.z, (cc).z, fmaf(qd.y, (cc).y, p0));       \
      float d2 = fmaf(-2.0f, dot, qd.w + (cc).w);                   \
      if (d2 <= dmax) { /* <= : boundary points admissible */       \
        stk[pc * TPB + t] = make_float2(d2, __int_as_float(mm));    \
        ++pc;                                                       \
      }                                                             \
    } while (0)
    PROC(c0, m0 + s + 0);
    PROC(c1, m0 + s + 1);
    PROC(c2, m0 + s + 2);
    PROC(c3, m0 + s + 3);
    if (__any(pc >= SDEPTH - 3)) FLUSH();
    PROC(c4, m0 + s + 4);
    PROC(c5, m0 + s + 5);
    PROC(c6, m0 + s + 6);
    PROC(c7, m0 + s + 7);
    if (__any(pc >= SDEPTH - 3)) FLUSH();
#undef PROC
  }
  FLUSH();

  __syncthreads();  // repurpose smem: transposed lists (conflict-free)
  float2* tl = (float2*)smem;               // [KNN][4*QPB] = 32 KB
  float2* al = (float2*)(smem + 32768);     // [KNN][QPB]   =  8 KB

  // ---- phase A: chunks 0..3 publish, 4-way stable merge -> al ----
  if (chunk < 4) {
#pragma unroll
    for (int j = 0; j < KNN; ++j)
      tl[j * (4 * QPB) + t] = make_float2(dist[j], __int_as_float(idx[j]));
  }
  __syncthreads();
  if (t < QPB) {
    int p[4] = {0, 0, 0, 0};
#pragma unroll 1
    for (int j = 0; j < KNN; ++j) {
      float bd = __builtin_inff();
      int bi = 0, bc = 0;
#pragma unroll
      for (int c = 0; c < 4; ++c) {
        bool v = p[c] < KNN;
        int pp = v ? p[c] : 0;
        float2 e = tl[pp * (4 * QPB) + t + c * QPB];
        float hd = v ? e.x : __builtin_inff();
        // strict < keeps the earliest chunk on ties (ascending index ranges)
        if (hd < bd || c == 0) { bd = hd; bi = __float_as_int(e.y); bc = c; }
      }
      al[j * QPB + t] = make_float2(bd, __int_as_float(bi));
#pragma unroll
      for (int c = 0; c < 4; ++c) p[c] += (bc == c);
    }
  }
  __syncthreads();

  // ---- phase B: chunks 4..7 publish (reuse region), 5-way merge -> out ----
  if (chunk >= 4) {
#pragma unroll
    for (int j = 0; j < KNN; ++j)
      tl[j * (4 * QPB) + (t - 4 * QPB)] = make_float2(dist[j], __int_as_float(idx[j]));
  }
  __syncthreads();
  if (t < QPB) {
    int p[5] = {0, 0, 0, 0, 0};  // 0 = al (chunks 0-3), 1..4 = chunks 4..7
    int* kn = knn + bq * KNN;
#pragma unroll 1
    for (int j = 0; j < KNN; ++j) {
      float bd;
      int bi, bc;
      {
        bool v = p[0] < KNN;
        int pp = v ? p[0] : 0;
        float2 e = al[pp * QPB + t];
        bd = v ? e.x : __builtin_inff();
        bi = __float_as_int(e.y);
        bc = 0;
      }
#pragma unroll
      for (int c = 0; c < 4; ++c) {
        bool v = p[c + 1] < KNN;
        int pp = v ? p[c + 1] : 0;
        float2 e = tl[pp * (4 * QPB) + t + c * QPB];
        float hd = v ? e.x : __builtin_inff();
        if (hd < bd) { bd = hd; bi = __float_as_int(e.y); bc = c + 1; }
      }
      kn[j] = bi;
#pragma unroll
      for (int c = 0; c < 5; ++c) p[c] += (bc == c);
    }
  }
}

__global__ void walk_kernel(const int* __restrict__ rand_k, const int* __restrict__ knn,
                            int* __restrict__ out) {
  int t = blockIdx.x * blockDim.x + threadIdx.x;
  if (t >= NB * NP) return;
  int b = t >> 13;
  int n = t & (NP - 1);
  int cur = n;
  int* o = out + t * CLEN;
  o[0] = cur;
#pragma unroll
  for (int l = 0; l < CLEN - 1; ++l) {
    int rk = rand_k[(l * NB + b) * NP + n];
    cur = knn[(b * NP + cur) * KNN + rk];
    o[l + 1] = cur;
  }
}

extern "C" void kernel_launch(void* const* d_in, const int* in_sizes, int n_in,
                              void* d_out, int out_size, void* d_ws, size_t ws_size,
                              hipStream_t stream) {
  const float* xyz = (const float*)d_in[0];
  const int* rand_k = (const int*)d_in[1];
  int* out = (int*)d_out;

  char* w = (char*)d_ws;
  float4* cand  = (float4*)(w);                       // 512 KB natural order
  float4* scand = (float4*)(w + 524288);              // 512 KB Morton-sorted
  int* sidx     = (int*)(w + 1048576);                // 128 KB
  float* thr    = (float*)(w + 1179648);              // 128 KB
  int* knnt     = (int*)(w + 1310720);                // 2 MB
  int* cellid   = (int*)(w + 3407872);                // 128 KB
  int* hist     = (int*)(w + 3538944);                // 64 KB
  int* cursor   = (int*)(w + 3604480);                // 64 KB (adjacent)
  int* offs     = (int*)(w + 3670016);                // 64 KB

  hipMemsetAsync(hist, 0, 131072, stream);  // hist + cursor

  bin_kernel<<<(NB * NP + 255) / 256, 256, 0, stream>>>(xyz, cellid, hist);
  scan_kernel<<<NB, 1024, 0, stream>>>(hist, offs);
  scatter_kernel<<<(NB * NP + 255) / 256, 256, 0, stream>>>(xyz, cellid, offs, cursor,
                                                            scand, sidx, cand);
  thresh_kernel<<<(NB * NP + 255) / 256, 256, 0, stream>>>(scand, sidx, thr);
  knn_kernel<<<(NB * NP) / QPB, TPB, 0, stream>>>(cand, thr, knnt);
  walk_kernel<<<(NB * NP + 255) / 256, 256, 0, stream>>>(rand_k, knnt, out);
}